// Round 8
// baseline (228.717 us; speedup 1.0000x reference)
//
#include <hip/hip_runtime.h>

constexpr int Bn = 2;
constexpr int Nn = 16384;
constexpr int Cc = 128;
constexpr int Vv = Nn * 3;          // 49152
constexpr int Pp = 4;
constexpr int SB = 48;              // sort chunks per sample (1024 elems each)
constexpr int HB = 96;              // rank chunks per sample (512 elems each)

// out layout (flat float32, reference return order)
constexpr size_t IND0  = 0;
constexpr size_t COOR0 = (size_t)Bn * Vv * 3;
constexpr size_t FEAT0 = COOR0 + (size_t)Bn * Vv * Pp * 3;
constexpr size_t MASK0 = FEAT0 + (size_t)Bn * Vv * Pp * Cc;

// ---------------- GEMM layer 1 (FP order byte-identical to R3) ----------------
__global__ __launch_bounds__(256) void gemm1(
    const float* __restrict__ A, const float* __restrict__ W,
    const float* __restrict__ bias, float* __restrict__ out,
    unsigned* __restrict__ HZ)
{
    __shared__ float As[64 * 36];
    __shared__ float Ws[128 * 36];

    int t = threadIdx.x;
    {   // zero the 3 hist buffers (independent data)
        int gid = blockIdx.x * 256 + t;
        if (gid < 3 * Bn * SB * 1024 / 4)
            ((uint4*)HZ)[gid] = make_uint4(0u, 0u, 0u, 0u);
    }

    int bid = blockIdx.x;
    int s = bid >> 8, rb = bid & 255;
    const float* Ag = A + (size_t)s * Nn * Cc + (size_t)rb * 64 * Cc;
    float* outg = out + (size_t)s * Nn * Cc + (size_t)rb * 64 * Cc;

    int tx = t & 15, ty = t >> 4;
    int arow = t >> 3, ac4 = (t & 7) * 4;

    float acc[4][8];
    #pragma unroll
    for (int i = 0; i < 4; ++i)
        #pragma unroll
        for (int j = 0; j < 8; ++j) acc[i][j] = 0.f;

    float4 aR[2], wR[4];
    #pragma unroll
    for (int r = 0; r < 2; ++r)
        aR[r] = *(const float4*)(Ag + (size_t)(arow + r * 32) * Cc + ac4);
    #pragma unroll
    for (int r = 0; r < 4; ++r)
        wR[r] = *(const float4*)(W + (size_t)(arow + r * 32) * Cc + ac4);

    for (int stage = 0; stage < 4; ++stage) {
        if (stage) __syncthreads();
        #pragma unroll
        for (int r = 0; r < 2; ++r)
            *(float4*)&As[(arow + r * 32) * 36 + ac4] = aR[r];
        #pragma unroll
        for (int r = 0; r < 4; ++r)
            *(float4*)&Ws[(arow + r * 32) * 36 + ac4] = wR[r];
        if (stage < 3) {
            int k1 = (stage + 1) * 32;
            #pragma unroll
            for (int r = 0; r < 2; ++r)
                aR[r] = *(const float4*)(Ag + (size_t)(arow + r * 32) * Cc + k1 + ac4);
            #pragma unroll
            for (int r = 0; r < 4; ++r)
                wR[r] = *(const float4*)(W + (size_t)(arow + r * 32) * Cc + k1 + ac4);
        }
        __syncthreads();
        #pragma unroll
        for (int k4 = 0; k4 < 8; ++k4) {
            int k = k4 * 4;
            float4 av[4];
            #pragma unroll
            for (int i = 0; i < 4; ++i) av[i] = *(const float4*)&As[(i * 16 + ty) * 36 + k];
            #pragma unroll
            for (int j = 0; j < 8; ++j) {
                float4 wv = *(const float4*)&Ws[(j * 16 + tx) * 36 + k];
                #pragma unroll
                for (int i = 0; i < 4; ++i) {
                    float a0 = acc[i][j];
                    a0 = fmaf(av[i].x, wv.x, a0);
                    a0 = fmaf(av[i].y, wv.y, a0);
                    a0 = fmaf(av[i].z, wv.z, a0);
                    a0 = fmaf(av[i].w, wv.w, a0);
                    acc[i][j] = a0;
                }
            }
        }
    }
    #pragma unroll
    for (int j = 0; j < 8; ++j) {
        int col = j * 16 + tx;
        float bv = bias[col];
        #pragma unroll
        for (int i = 0; i < 4; ++i)
            outg[(size_t)(i * 16 + ty) * Cc + col] = acc[i][j] + bv;
    }
}

// ---------------- GEMM layer 2: redundant bnf + BN-fused A-load (as R7) -----------
__global__ __launch_bounds__(256) void gemm_t2(
    const float* __restrict__ A, const float* __restrict__ W,
    const float* __restrict__ bias, const float* __restrict__ part,
    const float* __restrict__ g, const float* __restrict__ be,
    float* __restrict__ out)
{
    __shared__ float As[64 * 36];
    __shared__ float Ws[128 * 36];
    __shared__ float ssl[2 * Cc];

    int t = threadIdx.x;
    int bid = blockIdx.x;
    int s = bid >> 8, rb = bid & 255;
    const float* Ag = A + (size_t)s * Nn * Cc + (size_t)rb * 64 * Cc;
    float* outg = out + (size_t)s * Nn * Cc + (size_t)rb * 64 * Cc;

    if (t < Cc) {       // redundant per-block bnfinalize: bitwise == R3's SS
        const float* pp = part + (size_t)s * 64 * 2 * Cc;
        float sm = 0.f, sq = 0.f;
        #pragma unroll 8
        for (int b = 0; b < 64; ++b) {
            sm += pp[(size_t)b * 2 * Cc + t];
            sq += pp[(size_t)b * 2 * Cc + Cc + t];
        }
        float m   = sm / (float)Nn;
        float var = sq / (float)Nn - m * m;
        float inv = 1.0f / sqrtf(var + 1e-5f);
        float sc  = g[t] * inv;
        ssl[t]      = sc;
        ssl[Cc + t] = be[t] - m * sc;
    }
    __syncthreads();

    int tx = t & 15, ty = t >> 4;
    int arow = t >> 3, ac4 = (t & 7) * 4;

    float acc[4][8];
    #pragma unroll
    for (int i = 0; i < 4; ++i)
        #pragma unroll
        for (int j = 0; j < 8; ++j) acc[i][j] = 0.f;

    float4 aR[2], wR[4];
    #pragma unroll
    for (int r = 0; r < 2; ++r)
        aR[r] = *(const float4*)(Ag + (size_t)(arow + r * 32) * Cc + ac4);
    #pragma unroll
    for (int r = 0; r < 4; ++r)
        wR[r] = *(const float4*)(W + (size_t)(arow + r * 32) * Cc + ac4);

    for (int stage = 0; stage < 4; ++stage) {
        int k0 = stage * 32;
        if (stage) __syncthreads();
        #pragma unroll
        for (int r = 0; r < 2; ++r) {
            float4 v = aR[r];
            int ch = k0 + ac4;
            v.x = fmaxf(0.f, fmaf(v.x, ssl[ch + 0], ssl[Cc + ch + 0]));
            v.y = fmaxf(0.f, fmaf(v.y, ssl[ch + 1], ssl[Cc + ch + 1]));
            v.z = fmaxf(0.f, fmaf(v.z, ssl[ch + 2], ssl[Cc + ch + 2]));
            v.w = fmaxf(0.f, fmaf(v.w, ssl[ch + 3], ssl[Cc + ch + 3]));
            *(float4*)&As[(arow + r * 32) * 36 + ac4] = v;
        }
        #pragma unroll
        for (int r = 0; r < 4; ++r)
            *(float4*)&Ws[(arow + r * 32) * 36 + ac4] = wR[r];
        if (stage < 3) {
            int k1 = k0 + 32;
            #pragma unroll
            for (int r = 0; r < 2; ++r)
                aR[r] = *(const float4*)(Ag + (size_t)(arow + r * 32) * Cc + k1 + ac4);
            #pragma unroll
            for (int r = 0; r < 4; ++r)
                wR[r] = *(const float4*)(W + (size_t)(arow + r * 32) * Cc + k1 + ac4);
        }
        __syncthreads();
        #pragma unroll
        for (int k4 = 0; k4 < 8; ++k4) {
            int k = k4 * 4;
            float4 av[4];
            #pragma unroll
            for (int i = 0; i < 4; ++i) av[i] = *(const float4*)&As[(i * 16 + ty) * 36 + k];
            #pragma unroll
            for (int j = 0; j < 8; ++j) {
                float4 wv = *(const float4*)&Ws[(j * 16 + tx) * 36 + k];
                #pragma unroll
                for (int i = 0; i < 4; ++i) {
                    float a0 = acc[i][j];
                    a0 = fmaf(av[i].x, wv.x, a0);
                    a0 = fmaf(av[i].y, wv.y, a0);
                    a0 = fmaf(av[i].z, wv.z, a0);
                    a0 = fmaf(av[i].w, wv.w, a0);
                    acc[i][j] = a0;
                }
            }
        }
    }
    #pragma unroll
    for (int j = 0; j < 8; ++j) {
        int col = j * 16 + tx;
        float bv = bias[col];
        #pragma unroll
        for (int i = 0; i < 4; ++i)
            outg[(size_t)(i * 16 + ty) * Cc + col] = acc[i][j] + bv;
    }
}

// ---------------- GEMM layer 3 + fused vote prep + redundant bnf (as R7) ----------
__global__ __launch_bounds__(256) void gemm3_fused(
    const float* __restrict__ A, const float* __restrict__ W,
    const float* __restrict__ bias, const float* __restrict__ part,
    const float* __restrict__ g, const float* __restrict__ be,
    const float* __restrict__ FT, const float* __restrict__ CO,
    const int* __restrict__ ID,
    float* __restrict__ featb, float* __restrict__ coor,
    int* __restrict__ indb, unsigned* __restrict__ keys,
    unsigned* __restrict__ idx0, unsigned* __restrict__ hist0)
{
    __shared__ float As[64 * 36];
    __shared__ float Ws[144 * 36];
    __shared__ float ssl[2 * Cc];

    int bid = blockIdx.x;
    int s = bid >> 8, rb = bid & 255;
    const float* Ag = A + (size_t)s * Nn * Cc + (size_t)rb * 64 * Cc;

    int t = threadIdx.x, tx = t & 15, ty = t >> 4;

    if (t < Cc) {       // redundant per-block bnfinalize (bitwise == R3's SS)
        const float* pp = part + (size_t)s * 64 * 2 * Cc;
        float sm = 0.f, sq = 0.f;
        #pragma unroll 8
        for (int b = 0; b < 64; ++b) {
            sm += pp[(size_t)b * 2 * Cc + t];
            sq += pp[(size_t)b * 2 * Cc + Cc + t];
        }
        float m   = sm / (float)Nn;
        float var = sq / (float)Nn - m * m;
        float inv = 1.0f / sqrtf(var + 1e-5f);
        float sc  = g[t] * inv;
        ssl[t]      = sc;
        ssl[Cc + t] = be[t] - m * sc;
    }
    __syncthreads();

    float acc[4][9];
    #pragma unroll
    for (int i = 0; i < 4; ++i)
        #pragma unroll
        for (int j = 0; j < 9; ++j) acc[i][j] = 0.f;

    for (int stage = 0; stage < 4; ++stage) {
        int k0 = stage * 32;
        if (stage) __syncthreads();
        #pragma unroll
        for (int r = 0; r < 2; ++r) {
            int idx = r * 256 + t;
            int row = idx >> 3, c4 = (idx & 7) * 4;
            float4 v = *(const float4*)(Ag + (size_t)row * Cc + k0 + c4);
            int ch = k0 + c4;
            v.x = fmaxf(0.f, fmaf(v.x, ssl[ch + 0], ssl[Cc + ch + 0]));
            v.y = fmaxf(0.f, fmaf(v.y, ssl[ch + 1], ssl[Cc + ch + 1]));
            v.z = fmaxf(0.f, fmaf(v.z, ssl[ch + 2], ssl[Cc + ch + 2]));
            v.w = fmaxf(0.f, fmaf(v.w, ssl[ch + 3], ssl[Cc + ch + 3]));
            *(float4*)&As[row * 36 + c4] = v;
        }
        for (int idx = t; idx < 144 * 8; idx += 256) {
            int row = idx >> 3, c4 = (idx & 7) * 4;
            float4 v = make_float4(0.f, 0.f, 0.f, 0.f);
            if (row < 137) {
                int wr = (row < 9) ? (row / 3) * 131 + (row % 3) : row + 256;
                v = *(const float4*)(W + (size_t)wr * Cc + k0 + c4);
            }
            *(float4*)&Ws[row * 36 + c4] = v;
        }
        __syncthreads();
        #pragma unroll
        for (int k4 = 0; k4 < 8; ++k4) {
            int k = k4 * 4;
            float4 av[4];
            #pragma unroll
            for (int i = 0; i < 4; ++i) av[i] = *(const float4*)&As[(i * 16 + ty) * 36 + k];
            #pragma unroll
            for (int j = 0; j < 9; ++j) {
                float4 wv = *(const float4*)&Ws[(j * 16 + tx) * 36 + k];
                #pragma unroll
                for (int i = 0; i < 4; ++i) {
                    float a0 = acc[i][j];
                    a0 = fmaf(av[i].x, wv.x, a0);
                    a0 = fmaf(av[i].y, wv.y, a0);
                    a0 = fmaf(av[i].z, wv.z, a0);
                    a0 = fmaf(av[i].w, wv.w, a0);
                    acc[i][j] = a0;
                }
            }
        }
    }

    __syncthreads();
    __shared__ float L9[64 * 12];
    int n0 = rb * 64;
    const float* FTg = FT + ((size_t)s * Nn + n0) * Cc;
    float* FBg = featb + ((size_t)s * Nn + n0) * Cc;
    #pragma unroll
    for (int j = 0; j < 9; ++j) {
        int col = j * 16 + tx;
        if (col < 9) {
            float bv = bias[(col / 3) * 131 + col % 3];
            #pragma unroll
            for (int i = 0; i < 4; ++i)
                L9[(i * 16 + ty) * 12 + col] = acc[i][j] + bv;
        } else if (col < 137) {
            int ch = col - 9;
            float bv = bias[col + 256];
            #pragma unroll
            for (int i = 0; i < 4; ++i) {
                int row = i * 16 + ty;
                float lg = acc[i][j] + bv;
                FBg[(size_t)row * Cc + ch] = FTg[(size_t)row * Cc + ch] + lg;
            }
        }
    }
    __syncthreads();
    if (t < 192) {
        int row = t / 3, jv = t - row * 3;
        int n = n0 + row, v = n * 3 + jv;
        size_t vb = (size_t)s * Vv + v;
        float o0 = L9[row * 12 + jv * 3 + 0];
        float o1 = L9[row * 12 + jv * 3 + 1];
        float o2 = L9[row * 12 + jv * 3 + 2];
        const float* co = CO + ((size_t)s * Nn + n) * 3;
        coor[vb * 3 + 0] = co[0] + o0;
        coor[vb * 3 + 1] = co[1] + o1;
        coor[vb * 3 + 2] = co[2] + o2;
        const int* id = ID + ((size_t)s * Nn + n) * 3;
        int gi0 = (int)(o0 / 0.1f), gi1 = (int)(o1 / 0.1f), gi2 = (int)(o2 / 0.1f);
        int i0 = id[0] + gi0, i1 = id[1] + gi1, i2 = id[2] + gi2;
        indb[vb * 3 + 0] = i0; indb[vb * 3 + 1] = i1; indb[vb * 3 + 2] = i2;
        int h0 = min(max(i0, -512), 511) + 512;
        int h1 = min(max(i1, -512), 511) + 512;
        int h2 = min(max(i2, -512), 511) + 512;
        unsigned key = ((unsigned)h0 * 1024u + (unsigned)h1) * 1024u + (unsigned)h2;
        keys[vb] = key;
        idx0[vb] = (unsigned)v;
        atomicAdd(&hist0[(size_t)s * SB * 1024 + (size_t)(v >> 10) * 1024 + (key & 1023u)], 1u);
    }
}

// ---------------- column stats: unroll 8 for load pipelining (order unchanged) ----
__global__ void colstats(const float* __restrict__ Y, float* __restrict__ part)
{
    int blk = blockIdx.x;
    int s = blk >> 6, b = blk & 63;
    const float* Yp = Y + (size_t)s * Nn * Cc + (size_t)b * 256 * Cc;
    int c = threadIdx.x;
    float sm = 0.f, sq = 0.f;
    #pragma unroll 8
    for (int r = 0; r < 256; ++r) {
        float v = Yp[(size_t)r * Cc + c];
        sm += v; sq += v * v;
    }
    float* pp = part + ((size_t)s * 64 + b) * 2 * Cc;
    pp[c] = sm;
    pp[Cc + c] = sq;
}

// ---------------- fused scan + stable scatter; wave-shuffle digit scan ------------
template<int PASS>
__global__ __launch_bounds__(512) void scat(
    const unsigned* __restrict__ kIn, const unsigned* __restrict__ iIn,
    unsigned* __restrict__ kOut, unsigned* __restrict__ iOut,
    const unsigned* __restrict__ hist, unsigned* __restrict__ nextH)
{
    __shared__ unsigned hw[8 * 1024];
    __shared__ unsigned tot[1024];
    __shared__ unsigned wtot[8];
    int t = threadIdx.x, lane = t & 63, w = t >> 6;
    int blk = blockIdx.x, s = blk / SB, b = blk % SB;

    #pragma unroll
    for (int i = 0; i < 16; ++i) hw[w * 1024 + i * 64 + lane] = 0u;

    // hist block-prefix + totals (2 digits/thread)
    const uint2* hs2 = (const uint2*)(hist + (size_t)s * SB * 1024);
    int d0 = 2 * t, d1 = 2 * t + 1;
    unsigned run0 = 0, run1 = 0, my0 = 0, my1 = 0;
    #pragma unroll 4
    for (int bb = 0; bb < SB; ++bb) {
        uint2 v = hs2[bb * 512 + t];
        if (bb == b) { my0 = run0; my1 = run1; }
        run0 += v.x; run1 += v.y;
    }
    // wave shuffle scan over pair sums (digits 128w .. 128w+127, barrier-free)
    unsigned pair = run0 + run1;
    unsigned S = pair;
    #pragma unroll
    for (int o = 1; o < 64; o <<= 1) {
        unsigned v = __shfl_up(S, o);
        if (lane >= o) S += v;
    }
    unsigned pairExcl = S - pair;
    unsigned wTot = __shfl(S, 63);
    if (lane == 63) wtot[w] = S;
    __syncthreads();
    unsigned waveBase = 0;
    #pragma unroll
    for (int ww = 0; ww < 8; ++ww)
        if (ww < w) waveBase += wtot[ww];
    (void)wTot;
    // tot[d] := global-exclusive digit base + my-block prefix within digit
    tot[d0] = waveBase + pairExcl + my0;
    tot[d1] = waveBase + pairExcl + run0 + my1;

    // stable in-block ranking: wave chunks of 128, 2 slots of 64 (position order)
    size_t base = (size_t)s * Vv + (size_t)b * 1024;
    unsigned keyE[2], idxE[2], rkE[2], dE[2];
    #pragma unroll
    for (int e = 0; e < 2; ++e) {
        int pos = w * 128 + e * 64 + lane;
        keyE[e] = kIn[base + pos];
        idxE[e] = iIn[base + pos];
        unsigned d = (keyE[e] >> (PASS * 10)) & 1023u;
        dE[e] = d;
        unsigned long long m = ~0ull;
        #pragma unroll
        for (int bit = 0; bit < 10; ++bit) {
            bool bbit = (d >> bit) & 1u;
            unsigned long long bal = __ballot(bbit);
            m &= bbit ? bal : ~bal;
        }
        int lanesBelow = __popcll(m & ((1ull << lane) - 1ull));
        int cnt = __popcll(m);
        int leader = __ffsll((unsigned long long)m) - 1;
        unsigned basec = hw[w * 1024 + d];
        if (lane == leader) hw[w * 1024 + d] = basec + (unsigned)cnt;
        rkE[e] = basec + (unsigned)lanesBelow;
    }
    __syncthreads();
    {   // hw rows -> cross-wave exclusive offsets, in place
        unsigned r0 = 0, r1 = 0;
        for (int ww = 0; ww < 8; ++ww) {
            unsigned v0 = hw[ww * 1024 + d0], v1 = hw[ww * 1024 + d1];
            hw[ww * 1024 + d0] = r0; hw[ww * 1024 + d1] = r1;
            r0 += v0; r1 += v1;
        }
    }
    __syncthreads();
    #pragma unroll
    for (int e = 0; e < 2; ++e) {
        unsigned dest = tot[dE[e]] + hw[w * 1024 + dE[e]] + rkE[e];
        kOut[(size_t)s * Vv + dest] = keyE[e];
        iOut[(size_t)s * Vv + dest] = idxE[e];
        if constexpr (PASS < 2) {
            unsigned d2 = (keyE[e] >> ((PASS + 1) * 10)) & 1023u;
            atomicAdd(&nextH[(size_t)s * SB * 1024 + (size_t)(dest >> 10) * 1024 + d2], 1u);
        }
    }
}

// ------- ranksall: self-computed chunk head-counts + prefix + group starts --------
__global__ __launch_bounds__(512) void ranksall(const unsigned* __restrict__ skeys,
                                                unsigned* __restrict__ start,
                                                unsigned* __restrict__ nu)
{   // grid: Bn*HB blocks, 512 threads
    int blk = blockIdx.x;
    int s = blk / HB, cb = blk % HB;
    int t = threadIdx.x, lane = t & 63, w = t >> 6;
    size_t base = (size_t)s * Vv;

    __shared__ unsigned cnt[HB];
    __shared__ unsigned pre[HB + 1];
    __shared__ unsigned wsum[8];

    // phase 1: wave w counts heads of chunks w*12 .. w*12+11 (barrier-free)
    for (int cc = w * 12; cc < w * 12 + 12; ++cc) {
        unsigned tc = 0;
        #pragma unroll
        for (int sub = 0; sub < 8; ++sub) {
            int i = cc * 512 + sub * 64 + lane;
            unsigned k = skeys[base + i];
            bool head = (i == 0) || (skeys[base + i - 1] != k);
            tc += (unsigned)__popcll(__ballot(head));
        }
        if (lane == 0) cnt[cc] = tc;
    }
    __syncthreads();
    if (t == 0) {
        unsigned run = 0;
        for (int i = 0; i < HB; ++i) { pre[i] = run; run += cnt[i]; }
        pre[HB] = run;
    }
    __syncthreads();

    // phase 2: own chunk's head positions
    int i = cb * 512 + t;
    unsigned k = skeys[base + i];
    bool head = (i == 0) || (skeys[base + i - 1] != k);
    unsigned long long bal = __ballot(head);
    if (lane == 0) wsum[w] = (unsigned)__popcll(bal);
    __syncthreads();
    unsigned wbase = 0;
    for (int ww = 0; ww < w; ++ww) wbase += wsum[ww];
    unsigned lpre = (unsigned)__popcll(bal & ((1ull << lane) - 1ull));
    if (head)
        start[(size_t)s * (Vv + 1) + pre[cb] + wbase + lpre] = (unsigned)i;
    if (cb == 0 && t == 0) {
        nu[s] = pre[HB];
        start[(size_t)s * (Vv + 1) + pre[HB]] = (unsigned)Vv;
    }
}

// ---------------- output build: 8 rows per 512-thr block ----------------
__global__ __launch_bounds__(512) void outputk(
    const unsigned* __restrict__ sidx, const unsigned* __restrict__ start,
    const unsigned* __restrict__ nu, const int* __restrict__ indb,
    const float* __restrict__ coor, const float* __restrict__ featb,
    float* __restrict__ out)
{
    int wid = threadIdx.x >> 6, lane = threadIdx.x & 63;
    int g = blockIdx.x * 8 + wid;
    int s = g / Vv, u = g - s * Vv;
    size_t su = (size_t)s * Vv + u;
    bool valid = (unsigned)u < nu[s];
    float4* out4 = (float4*)out;
    int f = lane & 31, jlo = lane >> 5;
    if (valid) {
        const unsigned* st = start + (size_t)s * (Vv + 1);
        unsigned i0 = st[u], i1 = st[u + 1];
        unsigned c = i1 - i0;
        unsigned my = sidx[(size_t)s * Vv + i0 + ((unsigned)(lane & 3)) % c];
        unsigned sv[4];
        sv[0] = __shfl(my, 0); sv[1] = __shfl(my, 1);
        sv[2] = __shfl(my, 2); sv[3] = __shfl(my, 3);
        const float4* fb = (const float4*)(featb + (size_t)s * Nn * Cc);
        #pragma unroll
        for (int h = 0; h < 2; ++h) {
            int j = jlo + 2 * h;
            out4[(FEAT0 >> 2) + su * 128 + (size_t)j * 32 + f] =
                fb[(size_t)(sv[j] / 3) * 32 + f];
        }
        if (lane < 12)
            out[COOR0 + su * 12 + lane] =
                coor[((size_t)s * Vv + sv[lane / 3]) * 3 + lane % 3];
        else if (lane < 15)
            out[IND0 + su * 3 + (lane - 12)] =
                (float)indb[((size_t)s * Vv + sv[0]) * 3 + (lane - 12)];
        else if (lane == 15)
            out[MASK0 + su] = 1.f;
    } else {
        float4 z = make_float4(0.f, 0.f, 0.f, 0.f);
        #pragma unroll
        for (int h = 0; h < 2; ++h)
            out4[(FEAT0 >> 2) + su * 128 + (size_t)(jlo + 2 * h) * 32 + f] = z;
        if (lane < 12)       out[COOR0 + su * 12 + lane] = 0.f;
        else if (lane < 15)  out[IND0 + su * 3 + (lane - 12)] = 0.f;
        else if (lane == 15) out[MASK0 + su] = 0.f;
    }
}

// ---------------- host launch ----------------
extern "C" void kernel_launch(void* const* d_in, const int* in_sizes, int n_in,
                              void* d_out, int out_size, void* d_ws, size_t ws_size,
                              hipStream_t stream)
{
    const int*   ID  = (const int*)d_in[0];
    const float* CO  = (const float*)d_in[1];
    const float* FT  = (const float*)d_in[2];
    const float* W1  = (const float*)d_in[3];
    const float* b1  = (const float*)d_in[4];
    const float* g1  = (const float*)d_in[5];
    const float* be1 = (const float*)d_in[6];
    const float* W2  = (const float*)d_in[7];
    const float* b2  = (const float*)d_in[8];
    const float* g2  = (const float*)d_in[9];
    const float* be2 = (const float*)d_in[10];
    const float* W3  = (const float*)d_in[11];
    const float* b3  = (const float*)d_in[12];
    float* out = (float*)d_out;

    char* wsc = (char*)d_ws;
    size_t off = 0;
    auto alloc = [&](size_t elems) -> void* {
        void* p = wsc + off;
        off += ((elems * 4 + 255) & ~(size_t)255);
        return p;
    };
    float*    H1b   = (float*)alloc((size_t)Bn * Nn * Cc);
    float*    H2b   = (float*)alloc((size_t)Bn * Nn * Cc);
    float*    PART  = (float*)alloc((size_t)Bn * 64 * 2 * Cc);
    float*    COORb = (float*)alloc((size_t)Bn * Vv * 3);
    int*      INDB  = (int*)alloc((size_t)Bn * Vv * 3);
    float*    FEATB = (float*)alloc((size_t)Bn * Nn * Cc);
    unsigned* KA    = (unsigned*)alloc((size_t)Bn * Vv);
    unsigned* IA    = (unsigned*)alloc((size_t)Bn * Vv);
    unsigned* KB    = (unsigned*)alloc((size_t)Bn * Vv);
    unsigned* IB    = (unsigned*)alloc((size_t)Bn * Vv);
    unsigned* H0h   = (unsigned*)alloc((size_t)Bn * SB * 1024);  // three hist buffers,
    unsigned* H1h   = (unsigned*)alloc((size_t)Bn * SB * 1024);  // contiguous
    unsigned* H2h   = (unsigned*)alloc((size_t)Bn * SB * 1024);
    unsigned* NUp   = (unsigned*)alloc((size_t)Bn);
    unsigned* STp   = (unsigned*)alloc((size_t)Bn * (Vv + 1));
    (void)in_sizes; (void)n_in; (void)out_size; (void)ws_size;

    // 1: gemm1 + zero hists
    gemm1<<<Bn * 256, 256, 0, stream>>>(FT, W1, b1, H1b, H0h);
    // 2: stats layer1
    colstats<<<Bn * 64, 128, 0, stream>>>(H1b, PART);
    // 3: gemm2 (redundant bnf + BN-fused A-load, double-buffered)
    gemm_t2<<<Bn * 256, 256, 0, stream>>>(H1b, W2, b2, PART, g1, be1, H2b);
    // 4: stats layer2
    colstats<<<Bn * 64, 128, 0, stream>>>(H2b, PART);
    // 5: gemm3 (redundant bnf) + fused vote prep
    gemm3_fused<<<Bn * 256, 256, 0, stream>>>(
        H2b, W3, b3, PART, g2, be2, FT, CO, ID, FEATB, COORb, INDB, KA, IA, H0h);
    // 6-8: radix sort
    scat<0><<<Bn * SB, 512, 0, stream>>>(KA, IA, KB, IB, H0h, H1h);
    scat<1><<<Bn * SB, 512, 0, stream>>>(KB, IB, KA, IA, H1h, H2h);
    scat<2><<<Bn * SB, 512, 0, stream>>>(KA, IA, KB, IB, H2h, nullptr);
    // 9: grouping (heads folded into ranks)
    ranksall<<<Bn * HB, 512, 0, stream>>>(KB, STp, NUp);
    // 10: output
    outputk<<<Bn * Vv / 8, 512, 0, stream>>>(IB, STp, NUp, INDB, COORb, FEATB, out);
}

// Round 9
// 224.059 us; speedup vs baseline: 1.0208x; 1.0208x over previous
//
#include <hip/hip_runtime.h>

constexpr int Bn = 2;
constexpr int Nn = 16384;
constexpr int Cc = 128;
constexpr int Vv = Nn * 3;          // 49152
constexpr int Pp = 4;
constexpr int SB = 48;              // sort chunks per sample (1024 elems each)
constexpr int HB = 96;              // head/rank chunks per sample (512 elems each)

// out layout (flat float32, reference return order)
constexpr size_t IND0  = 0;
constexpr size_t COOR0 = (size_t)Bn * Vv * 3;
constexpr size_t FEAT0 = COOR0 + (size_t)Bn * Vv * Pp * 3;
constexpr size_t MASK0 = FEAT0 + (size_t)Bn * Vv * Pp * Cc;

// ---------------- GEMM layer 1 (FP order byte-identical to R3/R7) ----------------
__global__ __launch_bounds__(256) void gemm1(
    const float* __restrict__ A, const float* __restrict__ W,
    const float* __restrict__ bias, float* __restrict__ out,
    unsigned* __restrict__ HZ)
{
    __shared__ float As[64 * 36];
    __shared__ float Ws[128 * 36];

    int t = threadIdx.x;
    {   // zero the 3 hist buffers (independent data)
        int gid = blockIdx.x * 256 + t;
        if (gid < 3 * Bn * SB * 1024 / 4)
            ((uint4*)HZ)[gid] = make_uint4(0u, 0u, 0u, 0u);
    }

    int bid = blockIdx.x;
    int s = bid >> 8, rb = bid & 255;
    const float* Ag = A + (size_t)s * Nn * Cc + (size_t)rb * 64 * Cc;
    float* outg = out + (size_t)s * Nn * Cc + (size_t)rb * 64 * Cc;

    int tx = t & 15, ty = t >> 4;
    int arow = t >> 3, ac4 = (t & 7) * 4;

    float acc[4][8];
    #pragma unroll
    for (int i = 0; i < 4; ++i)
        #pragma unroll
        for (int j = 0; j < 8; ++j) acc[i][j] = 0.f;

    float4 aR[2], wR[4];
    #pragma unroll
    for (int r = 0; r < 2; ++r)
        aR[r] = *(const float4*)(Ag + (size_t)(arow + r * 32) * Cc + ac4);
    #pragma unroll
    for (int r = 0; r < 4; ++r)
        wR[r] = *(const float4*)(W + (size_t)(arow + r * 32) * Cc + ac4);

    for (int stage = 0; stage < 4; ++stage) {
        if (stage) __syncthreads();
        #pragma unroll
        for (int r = 0; r < 2; ++r)
            *(float4*)&As[(arow + r * 32) * 36 + ac4] = aR[r];
        #pragma unroll
        for (int r = 0; r < 4; ++r)
            *(float4*)&Ws[(arow + r * 32) * 36 + ac4] = wR[r];
        if (stage < 3) {
            int k1 = (stage + 1) * 32;
            #pragma unroll
            for (int r = 0; r < 2; ++r)
                aR[r] = *(const float4*)(Ag + (size_t)(arow + r * 32) * Cc + k1 + ac4);
            #pragma unroll
            for (int r = 0; r < 4; ++r)
                wR[r] = *(const float4*)(W + (size_t)(arow + r * 32) * Cc + k1 + ac4);
        }
        __syncthreads();
        #pragma unroll
        for (int k4 = 0; k4 < 8; ++k4) {
            int k = k4 * 4;
            float4 av[4];
            #pragma unroll
            for (int i = 0; i < 4; ++i) av[i] = *(const float4*)&As[(i * 16 + ty) * 36 + k];
            #pragma unroll
            for (int j = 0; j < 8; ++j) {
                float4 wv = *(const float4*)&Ws[(j * 16 + tx) * 36 + k];
                #pragma unroll
                for (int i = 0; i < 4; ++i) {
                    float a0 = acc[i][j];
                    a0 = fmaf(av[i].x, wv.x, a0);
                    a0 = fmaf(av[i].y, wv.y, a0);
                    a0 = fmaf(av[i].z, wv.z, a0);
                    a0 = fmaf(av[i].w, wv.w, a0);
                    acc[i][j] = a0;
                }
            }
        }
    }
    #pragma unroll
    for (int j = 0; j < 8; ++j) {
        int col = j * 16 + tx;
        float bv = bias[col];
        #pragma unroll
        for (int i = 0; i < 4; ++i)
            outg[(size_t)(i * 16 + ty) * Cc + col] = acc[i][j] + bv;
    }
}

// ---------------- GEMM layer 2: redundant bnf + BN-fused A-load (as R7) -----------
__global__ __launch_bounds__(256) void gemm_t2(
    const float* __restrict__ A, const float* __restrict__ W,
    const float* __restrict__ bias, const float* __restrict__ part,
    const float* __restrict__ g, const float* __restrict__ be,
    float* __restrict__ out)
{
    __shared__ float As[64 * 36];
    __shared__ float Ws[128 * 36];
    __shared__ float ssl[2 * Cc];

    int t = threadIdx.x;
    int bid = blockIdx.x;
    int s = bid >> 8, rb = bid & 255;
    const float* Ag = A + (size_t)s * Nn * Cc + (size_t)rb * 64 * Cc;
    float* outg = out + (size_t)s * Nn * Cc + (size_t)rb * 64 * Cc;

    if (t < Cc) {       // redundant per-block bnfinalize: bitwise == R3's SS
        const float* pp = part + (size_t)s * 64 * 2 * Cc;
        float sm = 0.f, sq = 0.f;
        for (int b = 0; b < 64; ++b) {
            sm += pp[(size_t)b * 2 * Cc + t];
            sq += pp[(size_t)b * 2 * Cc + Cc + t];
        }
        float m   = sm / (float)Nn;
        float var = sq / (float)Nn - m * m;
        float inv = 1.0f / sqrtf(var + 1e-5f);
        float sc  = g[t] * inv;
        ssl[t]      = sc;
        ssl[Cc + t] = be[t] - m * sc;
    }
    __syncthreads();

    int tx = t & 15, ty = t >> 4;
    int arow = t >> 3, ac4 = (t & 7) * 4;

    float acc[4][8];
    #pragma unroll
    for (int i = 0; i < 4; ++i)
        #pragma unroll
        for (int j = 0; j < 8; ++j) acc[i][j] = 0.f;

    float4 aR[2], wR[4];
    #pragma unroll
    for (int r = 0; r < 2; ++r)
        aR[r] = *(const float4*)(Ag + (size_t)(arow + r * 32) * Cc + ac4);
    #pragma unroll
    for (int r = 0; r < 4; ++r)
        wR[r] = *(const float4*)(W + (size_t)(arow + r * 32) * Cc + ac4);

    for (int stage = 0; stage < 4; ++stage) {
        int k0 = stage * 32;
        if (stage) __syncthreads();
        #pragma unroll
        for (int r = 0; r < 2; ++r) {
            float4 v = aR[r];
            int ch = k0 + ac4;
            v.x = fmaxf(0.f, fmaf(v.x, ssl[ch + 0], ssl[Cc + ch + 0]));
            v.y = fmaxf(0.f, fmaf(v.y, ssl[ch + 1], ssl[Cc + ch + 1]));
            v.z = fmaxf(0.f, fmaf(v.z, ssl[ch + 2], ssl[Cc + ch + 2]));
            v.w = fmaxf(0.f, fmaf(v.w, ssl[ch + 3], ssl[Cc + ch + 3]));
            *(float4*)&As[(arow + r * 32) * 36 + ac4] = v;
        }
        #pragma unroll
        for (int r = 0; r < 4; ++r)
            *(float4*)&Ws[(arow + r * 32) * 36 + ac4] = wR[r];
        if (stage < 3) {
            int k1 = k0 + 32;
            #pragma unroll
            for (int r = 0; r < 2; ++r)
                aR[r] = *(const float4*)(Ag + (size_t)(arow + r * 32) * Cc + k1 + ac4);
            #pragma unroll
            for (int r = 0; r < 4; ++r)
                wR[r] = *(const float4*)(W + (size_t)(arow + r * 32) * Cc + k1 + ac4);
        }
        __syncthreads();
        #pragma unroll
        for (int k4 = 0; k4 < 8; ++k4) {
            int k = k4 * 4;
            float4 av[4];
            #pragma unroll
            for (int i = 0; i < 4; ++i) av[i] = *(const float4*)&As[(i * 16 + ty) * 36 + k];
            #pragma unroll
            for (int j = 0; j < 8; ++j) {
                float4 wv = *(const float4*)&Ws[(j * 16 + tx) * 36 + k];
                #pragma unroll
                for (int i = 0; i < 4; ++i) {
                    float a0 = acc[i][j];
                    a0 = fmaf(av[i].x, wv.x, a0);
                    a0 = fmaf(av[i].y, wv.y, a0);
                    a0 = fmaf(av[i].z, wv.z, a0);
                    a0 = fmaf(av[i].w, wv.w, a0);
                    acc[i][j] = a0;
                }
            }
        }
    }
    #pragma unroll
    for (int j = 0; j < 8; ++j) {
        int col = j * 16 + tx;
        float bv = bias[col];
        #pragma unroll
        for (int i = 0; i < 4; ++i)
            outg[(size_t)(i * 16 + ty) * Cc + col] = acc[i][j] + bv;
    }
}

// ---------------- GEMM layer 3 + fused vote prep + redundant bnf (as R7) ----------
__global__ __launch_bounds__(256) void gemm3_fused(
    const float* __restrict__ A, const float* __restrict__ W,
    const float* __restrict__ bias, const float* __restrict__ part,
    const float* __restrict__ g, const float* __restrict__ be,
    const float* __restrict__ FT, const float* __restrict__ CO,
    const int* __restrict__ ID,
    float* __restrict__ featb, float* __restrict__ coor,
    int* __restrict__ indb, unsigned* __restrict__ keys,
    unsigned* __restrict__ idx0, unsigned* __restrict__ hist0)
{
    __shared__ float As[64 * 36];
    __shared__ float Ws[144 * 36];
    __shared__ float ssl[2 * Cc];

    int bid = blockIdx.x;
    int s = bid >> 8, rb = bid & 255;
    const float* Ag = A + (size_t)s * Nn * Cc + (size_t)rb * 64 * Cc;

    int t = threadIdx.x, tx = t & 15, ty = t >> 4;

    if (t < Cc) {       // redundant per-block bnfinalize (bitwise == R3's SS)
        const float* pp = part + (size_t)s * 64 * 2 * Cc;
        float sm = 0.f, sq = 0.f;
        for (int b = 0; b < 64; ++b) {
            sm += pp[(size_t)b * 2 * Cc + t];
            sq += pp[(size_t)b * 2 * Cc + Cc + t];
        }
        float m   = sm / (float)Nn;
        float var = sq / (float)Nn - m * m;
        float inv = 1.0f / sqrtf(var + 1e-5f);
        float sc  = g[t] * inv;
        ssl[t]      = sc;
        ssl[Cc + t] = be[t] - m * sc;
    }
    __syncthreads();

    float acc[4][9];
    #pragma unroll
    for (int i = 0; i < 4; ++i)
        #pragma unroll
        for (int j = 0; j < 9; ++j) acc[i][j] = 0.f;

    for (int stage = 0; stage < 4; ++stage) {
        int k0 = stage * 32;
        if (stage) __syncthreads();
        #pragma unroll
        for (int r = 0; r < 2; ++r) {
            int idx = r * 256 + t;
            int row = idx >> 3, c4 = (idx & 7) * 4;
            float4 v = *(const float4*)(Ag + (size_t)row * Cc + k0 + c4);
            int ch = k0 + c4;
            v.x = fmaxf(0.f, fmaf(v.x, ssl[ch + 0], ssl[Cc + ch + 0]));
            v.y = fmaxf(0.f, fmaf(v.y, ssl[ch + 1], ssl[Cc + ch + 1]));
            v.z = fmaxf(0.f, fmaf(v.z, ssl[ch + 2], ssl[Cc + ch + 2]));
            v.w = fmaxf(0.f, fmaf(v.w, ssl[ch + 3], ssl[Cc + ch + 3]));
            *(float4*)&As[row * 36 + c4] = v;
        }
        for (int idx = t; idx < 144 * 8; idx += 256) {
            int row = idx >> 3, c4 = (idx & 7) * 4;
            float4 v = make_float4(0.f, 0.f, 0.f, 0.f);
            if (row < 137) {
                int wr = (row < 9) ? (row / 3) * 131 + (row % 3) : row + 256;
                v = *(const float4*)(W + (size_t)wr * Cc + k0 + c4);
            }
            *(float4*)&Ws[row * 36 + c4] = v;
        }
        __syncthreads();
        #pragma unroll
        for (int k4 = 0; k4 < 8; ++k4) {
            int k = k4 * 4;
            float4 av[4];
            #pragma unroll
            for (int i = 0; i < 4; ++i) av[i] = *(const float4*)&As[(i * 16 + ty) * 36 + k];
            #pragma unroll
            for (int j = 0; j < 9; ++j) {
                float4 wv = *(const float4*)&Ws[(j * 16 + tx) * 36 + k];
                #pragma unroll
                for (int i = 0; i < 4; ++i) {
                    float a0 = acc[i][j];
                    a0 = fmaf(av[i].x, wv.x, a0);
                    a0 = fmaf(av[i].y, wv.y, a0);
                    a0 = fmaf(av[i].z, wv.z, a0);
                    a0 = fmaf(av[i].w, wv.w, a0);
                    acc[i][j] = a0;
                }
            }
        }
    }

    __syncthreads();
    __shared__ float L9[64 * 12];
    int n0 = rb * 64;
    const float* FTg = FT + ((size_t)s * Nn + n0) * Cc;
    float* FBg = featb + ((size_t)s * Nn + n0) * Cc;
    #pragma unroll
    for (int j = 0; j < 9; ++j) {
        int col = j * 16 + tx;
        if (col < 9) {
            float bv = bias[(col / 3) * 131 + col % 3];
            #pragma unroll
            for (int i = 0; i < 4; ++i)
                L9[(i * 16 + ty) * 12 + col] = acc[i][j] + bv;
        } else if (col < 137) {
            int ch = col - 9;
            float bv = bias[col + 256];
            #pragma unroll
            for (int i = 0; i < 4; ++i) {
                int row = i * 16 + ty;
                float lg = acc[i][j] + bv;
                FBg[(size_t)row * Cc + ch] = FTg[(size_t)row * Cc + ch] + lg;
            }
        }
    }
    __syncthreads();
    if (t < 192) {
        int row = t / 3, jv = t - row * 3;
        int n = n0 + row, v = n * 3 + jv;
        size_t vb = (size_t)s * Vv + v;
        float o0 = L9[row * 12 + jv * 3 + 0];
        float o1 = L9[row * 12 + jv * 3 + 1];
        float o2 = L9[row * 12 + jv * 3 + 2];
        const float* co = CO + ((size_t)s * Nn + n) * 3;
        coor[vb * 3 + 0] = co[0] + o0;
        coor[vb * 3 + 1] = co[1] + o1;
        coor[vb * 3 + 2] = co[2] + o2;
        const int* id = ID + ((size_t)s * Nn + n) * 3;
        int gi0 = (int)(o0 / 0.1f), gi1 = (int)(o1 / 0.1f), gi2 = (int)(o2 / 0.1f);
        int i0 = id[0] + gi0, i1 = id[1] + gi1, i2 = id[2] + gi2;
        indb[vb * 3 + 0] = i0; indb[vb * 3 + 1] = i1; indb[vb * 3 + 2] = i2;
        int h0 = min(max(i0, -512), 511) + 512;
        int h1 = min(max(i1, -512), 511) + 512;
        int h2 = min(max(i2, -512), 511) + 512;
        unsigned key = ((unsigned)h0 * 1024u + (unsigned)h1) * 1024u + (unsigned)h2;
        keys[vb] = key;
        idx0[vb] = (unsigned)v;
        atomicAdd(&hist0[(size_t)s * SB * 1024 + (size_t)(v >> 10) * 1024 + (key & 1023u)], 1u);
    }
}

// ------- column stats: unroll 8 (load batching only; FP add order unchanged) ------
__global__ void colstats(const float* __restrict__ Y, float* __restrict__ part)
{
    int blk = blockIdx.x;
    int s = blk >> 6, b = blk & 63;
    const float* Yp = Y + (size_t)s * Nn * Cc + (size_t)b * 256 * Cc;
    int c = threadIdx.x;
    float sm = 0.f, sq = 0.f;
    #pragma unroll 8
    for (int r = 0; r < 256; ++r) {
        float v = Yp[(size_t)r * Cc + c];
        sm += v; sq += v * v;
    }
    float* pp = part + ((size_t)s * 64 + b) * 2 * Cc;
    pp[c] = sm;
    pp[Cc + c] = sq;
}

// ------- fused scan + stable scatter; wave-shuffle digit scan (R8's, passed) ------
template<int PASS>
__global__ __launch_bounds__(512) void scat(
    const unsigned* __restrict__ kIn, const unsigned* __restrict__ iIn,
    unsigned* __restrict__ kOut, unsigned* __restrict__ iOut,
    const unsigned* __restrict__ hist, unsigned* __restrict__ nextH)
{
    __shared__ unsigned hw[8 * 1024];
    __shared__ unsigned tot[1024];
    __shared__ unsigned wtot[8];
    int t = threadIdx.x, lane = t & 63, w = t >> 6;
    int blk = blockIdx.x, s = blk / SB, b = blk % SB;

    #pragma unroll
    for (int i = 0; i < 16; ++i) hw[w * 1024 + i * 64 + lane] = 0u;

    // hist block-prefix + totals (2 digits/thread)
    const uint2* hs2 = (const uint2*)(hist + (size_t)s * SB * 1024);
    int d0 = 2 * t, d1 = 2 * t + 1;
    unsigned run0 = 0, run1 = 0, my0 = 0, my1 = 0;
    #pragma unroll 4
    for (int bb = 0; bb < SB; ++bb) {
        uint2 v = hs2[bb * 512 + t];
        if (bb == b) { my0 = run0; my1 = run1; }
        run0 += v.x; run1 += v.y;
    }
    // wave shuffle scan over pair sums (digits 128w .. 128w+127, barrier-free)
    unsigned pair = run0 + run1;
    unsigned S = pair;
    #pragma unroll
    for (int o = 1; o < 64; o <<= 1) {
        unsigned v = __shfl_up(S, o);
        if (lane >= o) S += v;
    }
    unsigned pairExcl = S - pair;
    if (lane == 63) wtot[w] = S;
    __syncthreads();
    unsigned waveBase = 0;
    #pragma unroll
    for (int ww = 0; ww < 8; ++ww)
        if (ww < w) waveBase += wtot[ww];
    // tot[d] := global-exclusive digit base + my-block prefix within digit
    tot[d0] = waveBase + pairExcl + my0;
    tot[d1] = waveBase + pairExcl + run0 + my1;

    // stable in-block ranking: wave chunks of 128, 2 slots of 64 (position order)
    size_t base = (size_t)s * Vv + (size_t)b * 1024;
    unsigned keyE[2], idxE[2], rkE[2], dE[2];
    #pragma unroll
    for (int e = 0; e < 2; ++e) {
        int pos = w * 128 + e * 64 + lane;
        keyE[e] = kIn[base + pos];
        idxE[e] = iIn[base + pos];
        unsigned d = (keyE[e] >> (PASS * 10)) & 1023u;
        dE[e] = d;
        unsigned long long m = ~0ull;
        #pragma unroll
        for (int bit = 0; bit < 10; ++bit) {
            bool bbit = (d >> bit) & 1u;
            unsigned long long bal = __ballot(bbit);
            m &= bbit ? bal : ~bal;
        }
        int lanesBelow = __popcll(m & ((1ull << lane) - 1ull));
        int cnt = __popcll(m);
        int leader = __ffsll((unsigned long long)m) - 1;
        unsigned basec = hw[w * 1024 + d];
        if (lane == leader) hw[w * 1024 + d] = basec + (unsigned)cnt;
        rkE[e] = basec + (unsigned)lanesBelow;
    }
    __syncthreads();
    {   // hw rows -> cross-wave exclusive offsets, in place
        unsigned r0 = 0, r1 = 0;
        for (int ww = 0; ww < 8; ++ww) {
            unsigned v0 = hw[ww * 1024 + d0], v1 = hw[ww * 1024 + d1];
            hw[ww * 1024 + d0] = r0; hw[ww * 1024 + d1] = r1;
            r0 += v0; r1 += v1;
        }
    }
    __syncthreads();
    #pragma unroll
    for (int e = 0; e < 2; ++e) {
        unsigned dest = tot[dE[e]] + hw[w * 1024 + dE[e]] + rkE[e];
        kOut[(size_t)s * Vv + dest] = keyE[e];
        iOut[(size_t)s * Vv + dest] = idxE[e];
        if constexpr (PASS < 2) {
            unsigned d2 = (keyE[e] >> ((PASS + 1) * 10)) & 1023u;
            atomicAdd(&nextH[(size_t)s * SB * 1024 + (size_t)(dest >> 10) * 1024 + d2], 1u);
        }
    }
}

// ---------------- group heads (per-block counts), as R7 ----------------
__global__ __launch_bounds__(512) void headsct(const unsigned* __restrict__ skeys,
                                               unsigned* __restrict__ hpart)
{
    int blk = blockIdx.x;
    int s = blk / HB, b = blk % HB;
    int i = b * 512 + threadIdx.x;
    size_t base = (size_t)s * Vv;
    unsigned k = skeys[base + i];
    bool head = (i == 0) || (skeys[base + i - 1] != k);
    __shared__ unsigned wsum[8];
    unsigned long long bal = __ballot(head);
    int lane = threadIdx.x & 63, wid = threadIdx.x >> 6;
    if (lane == 0) wsum[wid] = (unsigned)__popcll(bal);
    __syncthreads();
    if (threadIdx.x == 0) {
        unsigned tot = 0;
        for (int w = 0; w < 8; ++w) tot += wsum[w];
        hpart[s * HB + b] = tot;
    }
}

// ---------------- ranks: self-prefix + write group starts, as R7 ----------------
__global__ __launch_bounds__(512) void ranksk(const unsigned* __restrict__ skeys,
                                              const unsigned* __restrict__ hpart,
                                              unsigned* __restrict__ start,
                                              unsigned* __restrict__ nu)
{
    int blk = blockIdx.x;
    int s = blk / HB, b = blk % HB;
    int t = threadIdx.x;
    __shared__ unsigned hp[HB];
    __shared__ unsigned pre[HB + 1];
    if (t < HB) hp[t] = hpart[s * HB + t];
    __syncthreads();
    if (t == 0) {
        unsigned run = 0;
        for (int i = 0; i < HB; ++i) { pre[i] = run; run += hp[i]; }
        pre[HB] = run;
    }
    __syncthreads();
    int i = b * 512 + t;
    size_t base = (size_t)s * Vv;
    unsigned k = skeys[base + i];
    bool head = (i == 0) || (skeys[base + i - 1] != k);
    unsigned long long bal = __ballot(head);
    int lane = t & 63, wid = t >> 6;
    __shared__ unsigned wsum[8];
    if (lane == 0) wsum[wid] = (unsigned)__popcll(bal);
    __syncthreads();
    unsigned wbase = 0;
    for (int w = 0; w < wid; ++w) wbase += wsum[w];
    unsigned lpre = (unsigned)__popcll(bal & ((1ull << lane) - 1ull));
    if (head)
        start[(size_t)s * (Vv + 1) + pre[b] + wbase + lpre] = (unsigned)i;
    if (b == 0 && t == 0) {
        nu[s] = pre[HB];
        start[(size_t)s * (Vv + 1) + pre[HB]] = (unsigned)Vv;
    }
}

// ---------------- output build: 1 wave per output row (R3/R7 version) -------------
__global__ __launch_bounds__(256) void outputk(
    const unsigned* __restrict__ sidx, const unsigned* __restrict__ start,
    const unsigned* __restrict__ nu, const int* __restrict__ indb,
    const float* __restrict__ coor, const float* __restrict__ featb,
    float* __restrict__ out)
{
    int wid = threadIdx.x >> 6, lane = threadIdx.x & 63;
    int g = blockIdx.x * 4 + wid;
    int s = g / Vv, u = g - s * Vv;
    size_t su = (size_t)s * Vv + u;
    bool valid = (unsigned)u < nu[s];
    float4* out4 = (float4*)out;
    int f = lane & 31, jlo = lane >> 5;
    if (valid) {
        const unsigned* st = start + (size_t)s * (Vv + 1);
        unsigned i0 = st[u], i1 = st[u + 1];
        unsigned c = i1 - i0;
        unsigned my = sidx[(size_t)s * Vv + i0 + ((unsigned)(lane & 3)) % c];
        unsigned sv[4];
        sv[0] = __shfl(my, 0); sv[1] = __shfl(my, 1);
        sv[2] = __shfl(my, 2); sv[3] = __shfl(my, 3);
        const float4* fb = (const float4*)(featb + (size_t)s * Nn * Cc);
        #pragma unroll
        for (int h = 0; h < 2; ++h) {
            int j = jlo + 2 * h;
            out4[(FEAT0 >> 2) + su * 128 + (size_t)j * 32 + f] =
                fb[(size_t)(sv[j] / 3) * 32 + f];
        }
        if (lane < 12)
            out[COOR0 + su * 12 + lane] =
                coor[((size_t)s * Vv + sv[lane / 3]) * 3 + lane % 3];
        else if (lane < 15)
            out[IND0 + su * 3 + (lane - 12)] =
                (float)indb[((size_t)s * Vv + sv[0]) * 3 + (lane - 12)];
        else if (lane == 15)
            out[MASK0 + su] = 1.f;
    } else {
        float4 z = make_float4(0.f, 0.f, 0.f, 0.f);
        #pragma unroll
        for (int h = 0; h < 2; ++h)
            out4[(FEAT0 >> 2) + su * 128 + (size_t)(jlo + 2 * h) * 32 + f] = z;
        if (lane < 12)       out[COOR0 + su * 12 + lane] = 0.f;
        else if (lane < 15)  out[IND0 + su * 3 + (lane - 12)] = 0.f;
        else if (lane == 15) out[MASK0 + su] = 0.f;
    }
}

// ---------------- host launch ----------------
extern "C" void kernel_launch(void* const* d_in, const int* in_sizes, int n_in,
                              void* d_out, int out_size, void* d_ws, size_t ws_size,
                              hipStream_t stream)
{
    const int*   ID  = (const int*)d_in[0];
    const float* CO  = (const float*)d_in[1];
    const float* FT  = (const float*)d_in[2];
    const float* W1  = (const float*)d_in[3];
    const float* b1  = (const float*)d_in[4];
    const float* g1  = (const float*)d_in[5];
    const float* be1 = (const float*)d_in[6];
    const float* W2  = (const float*)d_in[7];
    const float* b2  = (const float*)d_in[8];
    const float* g2  = (const float*)d_in[9];
    const float* be2 = (const float*)d_in[10];
    const float* W3  = (const float*)d_in[11];
    const float* b3  = (const float*)d_in[12];
    float* out = (float*)d_out;

    char* wsc = (char*)d_ws;
    size_t off = 0;
    auto alloc = [&](size_t elems) -> void* {
        void* p = wsc + off;
        off += ((elems * 4 + 255) & ~(size_t)255);
        return p;
    };
    float*    H1b   = (float*)alloc((size_t)Bn * Nn * Cc);
    float*    H2b   = (float*)alloc((size_t)Bn * Nn * Cc);
    float*    PART  = (float*)alloc((size_t)Bn * 64 * 2 * Cc);
    float*    COORb = (float*)alloc((size_t)Bn * Vv * 3);
    int*      INDB  = (int*)alloc((size_t)Bn * Vv * 3);
    float*    FEATB = (float*)alloc((size_t)Bn * Nn * Cc);
    unsigned* KA    = (unsigned*)alloc((size_t)Bn * Vv);
    unsigned* IA    = (unsigned*)alloc((size_t)Bn * Vv);
    unsigned* KB    = (unsigned*)alloc((size_t)Bn * Vv);
    unsigned* IB    = (unsigned*)alloc((size_t)Bn * Vv);
    unsigned* H0h   = (unsigned*)alloc((size_t)Bn * SB * 1024);  // three hist buffers,
    unsigned* H1h   = (unsigned*)alloc((size_t)Bn * SB * 1024);  // contiguous
    unsigned* H2h   = (unsigned*)alloc((size_t)Bn * SB * 1024);
    unsigned* HP    = (unsigned*)alloc((size_t)Bn * HB);
    unsigned* NUp   = (unsigned*)alloc((size_t)Bn);
    unsigned* STp   = (unsigned*)alloc((size_t)Bn * (Vv + 1));
    (void)in_sizes; (void)n_in; (void)out_size; (void)ws_size;

    // 1: gemm1 + zero hists
    gemm1<<<Bn * 256, 256, 0, stream>>>(FT, W1, b1, H1b, H0h);
    // 2: stats layer1
    colstats<<<Bn * 64, 128, 0, stream>>>(H1b, PART);
    // 3: gemm2 (redundant bnf + BN-fused A-load, double-buffered)
    gemm_t2<<<Bn * 256, 256, 0, stream>>>(H1b, W2, b2, PART, g1, be1, H2b);
    // 4: stats layer2
    colstats<<<Bn * 64, 128, 0, stream>>>(H2b, PART);
    // 5: gemm3 (redundant bnf) + fused vote prep
    gemm3_fused<<<Bn * 256, 256, 0, stream>>>(
        H2b, W3, b3, PART, g2, be2, FT, CO, ID, FEATB, COORb, INDB, KA, IA, H0h);
    // 6-8: radix sort
    scat<0><<<Bn * SB, 512, 0, stream>>>(KA, IA, KB, IB, H0h, H1h);
    scat<1><<<Bn * SB, 512, 0, stream>>>(KB, IB, KA, IA, H1h, H2h);
    scat<2><<<Bn * SB, 512, 0, stream>>>(KA, IA, KB, IB, H2h, nullptr);
    // 9-10: grouping
    headsct<<<Bn * HB, 512, 0, stream>>>(KB, HP);
    ranksk<<<Bn * HB, 512, 0, stream>>>(KB, HP, STp, NUp);
    // 11: output
    outputk<<<Bn * Vv / 4, 256, 0, stream>>>(IB, STp, NUp, INDB, COORb, FEATB, out);
}

// Round 10
// 213.400 us; speedup vs baseline: 1.0718x; 1.0499x over previous
//
#include <hip/hip_runtime.h>

constexpr int Bn = 2;
constexpr int Nn = 16384;
constexpr int Cc = 128;
constexpr int Vv = Nn * 3;          // 49152
constexpr int Pp = 4;
constexpr int SB = 48;              // sort blocks per sample (1024 elems each)
constexpr int HB = 96;              // head/rank blocks per sample (512 elems each)

// out layout (flat float32, reference return order)
constexpr size_t IND0  = 0;
constexpr size_t COOR0 = (size_t)Bn * Vv * 3;
constexpr size_t FEAT0 = COOR0 + (size_t)Bn * Vv * Pp * 3;
constexpr size_t MASK0 = FEAT0 + (size_t)Bn * Vv * Pp * Cc;

// ---------------- GEMM layers 1/2: 64x128 tile, BK=32, micro 4x8 ----------------
template<bool BN>
__global__ __launch_bounds__(256) void gemm_t(
    const float* __restrict__ A, const float* __restrict__ W,
    const float* __restrict__ bias, const float* __restrict__ ss,
    float* __restrict__ out)
{
    __shared__ float As[64 * 36];
    __shared__ float Ws[128 * 36];

    int bid = blockIdx.x;
    int s = bid >> 8, rb = bid & 255;
    const float* Ag = A + (size_t)s * Nn * Cc + (size_t)rb * 64 * Cc;
    float* outg = out + (size_t)s * Nn * Cc + (size_t)rb * 64 * Cc;
    const float* sp = nullptr;
    if constexpr (BN) sp = ss + (size_t)s * 2 * Cc;

    int t = threadIdx.x, tx = t & 15, ty = t >> 4;

    float acc[4][8];
    #pragma unroll
    for (int i = 0; i < 4; ++i)
        #pragma unroll
        for (int j = 0; j < 8; ++j) acc[i][j] = 0.f;

    for (int stage = 0; stage < 4; ++stage) {
        int k0 = stage * 32;
        if (stage) __syncthreads();
        #pragma unroll
        for (int r = 0; r < 2; ++r) {
            int idx = r * 256 + t;
            int row = idx >> 3, c4 = (idx & 7) * 4;
            float4 v = *(const float4*)(Ag + (size_t)row * Cc + k0 + c4);
            if constexpr (BN) {
                int ch = k0 + c4;
                v.x = fmaxf(0.f, fmaf(v.x, sp[ch + 0], sp[Cc + ch + 0]));
                v.y = fmaxf(0.f, fmaf(v.y, sp[ch + 1], sp[Cc + ch + 1]));
                v.z = fmaxf(0.f, fmaf(v.z, sp[ch + 2], sp[Cc + ch + 2]));
                v.w = fmaxf(0.f, fmaf(v.w, sp[ch + 3], sp[Cc + ch + 3]));
            }
            *(float4*)&As[row * 36 + c4] = v;
        }
        #pragma unroll
        for (int r = 0; r < 4; ++r) {
            int idx = r * 256 + t;
            int row = idx >> 3, c4 = (idx & 7) * 4;
            *(float4*)&Ws[row * 36 + c4] = *(const float4*)(W + (size_t)row * Cc + k0 + c4);
        }
        __syncthreads();
        #pragma unroll
        for (int k4 = 0; k4 < 8; ++k4) {
            int k = k4 * 4;
            float4 av[4];
            #pragma unroll
            for (int i = 0; i < 4; ++i) av[i] = *(const float4*)&As[(i * 16 + ty) * 36 + k];
            #pragma unroll
            for (int j = 0; j < 8; ++j) {
                float4 wv = *(const float4*)&Ws[(j * 16 + tx) * 36 + k];
                #pragma unroll
                for (int i = 0; i < 4; ++i) {
                    float a0 = acc[i][j];
                    a0 = fmaf(av[i].x, wv.x, a0);
                    a0 = fmaf(av[i].y, wv.y, a0);
                    a0 = fmaf(av[i].z, wv.z, a0);
                    a0 = fmaf(av[i].w, wv.w, a0);
                    acc[i][j] = a0;
                }
            }
        }
    }
    #pragma unroll
    for (int j = 0; j < 8; ++j) {
        int col = j * 16 + tx;
        float bv = bias[col];
        #pragma unroll
        for (int i = 0; i < 4; ++i)
            outg[(size_t)(i * 16 + ty) * Cc + col] = acc[i][j] + bv;
    }
}

// ---------------- GEMM layer 3 + fused vote prep ----------------
// Compact 137 cols: col<9 -> W3 row (col/3)*131+col%3 ; col in [9,137) -> row col+256.
__global__ __launch_bounds__(256) void gemm3_fused(
    const float* __restrict__ A, const float* __restrict__ W,
    const float* __restrict__ bias, const float* __restrict__ ss,
    const float* __restrict__ FT, const float* __restrict__ CO,
    const int* __restrict__ ID,
    float* __restrict__ featb, float* __restrict__ coor,
    int* __restrict__ indb, unsigned* __restrict__ keys,
    unsigned* __restrict__ idx0, unsigned* __restrict__ hist0)
{
    __shared__ float As[64 * 36];
    __shared__ float Ws[144 * 36];

    int bid = blockIdx.x;
    int s = bid >> 8, rb = bid & 255;
    const float* Ag = A + (size_t)s * Nn * Cc + (size_t)rb * 64 * Cc;
    const float* sp = ss + (size_t)s * 2 * Cc;

    int t = threadIdx.x, tx = t & 15, ty = t >> 4;

    float acc[4][9];
    #pragma unroll
    for (int i = 0; i < 4; ++i)
        #pragma unroll
        for (int j = 0; j < 9; ++j) acc[i][j] = 0.f;

    for (int stage = 0; stage < 4; ++stage) {
        int k0 = stage * 32;
        if (stage) __syncthreads();
        #pragma unroll
        for (int r = 0; r < 2; ++r) {
            int idx = r * 256 + t;
            int row = idx >> 3, c4 = (idx & 7) * 4;
            float4 v = *(const float4*)(Ag + (size_t)row * Cc + k0 + c4);
            int ch = k0 + c4;
            v.x = fmaxf(0.f, fmaf(v.x, sp[ch + 0], sp[Cc + ch + 0]));
            v.y = fmaxf(0.f, fmaf(v.y, sp[ch + 1], sp[Cc + ch + 1]));
            v.z = fmaxf(0.f, fmaf(v.z, sp[ch + 2], sp[Cc + ch + 2]));
            v.w = fmaxf(0.f, fmaf(v.w, sp[ch + 3], sp[Cc + ch + 3]));
            *(float4*)&As[row * 36 + c4] = v;
        }
        for (int idx = t; idx < 144 * 8; idx += 256) {
            int row = idx >> 3, c4 = (idx & 7) * 4;
            float4 v = make_float4(0.f, 0.f, 0.f, 0.f);
            if (row < 137) {
                int wr = (row < 9) ? (row / 3) * 131 + (row % 3) : row + 256;
                v = *(const float4*)(W + (size_t)wr * Cc + k0 + c4);
            }
            *(float4*)&Ws[row * 36 + c4] = v;
        }
        __syncthreads();
        #pragma unroll
        for (int k4 = 0; k4 < 8; ++k4) {
            int k = k4 * 4;
            float4 av[4];
            #pragma unroll
            for (int i = 0; i < 4; ++i) av[i] = *(const float4*)&As[(i * 16 + ty) * 36 + k];
            #pragma unroll
            for (int j = 0; j < 9; ++j) {
                float4 wv = *(const float4*)&Ws[(j * 16 + tx) * 36 + k];
                #pragma unroll
                for (int i = 0; i < 4; ++i) {
                    float a0 = acc[i][j];
                    a0 = fmaf(av[i].x, wv.x, a0);
                    a0 = fmaf(av[i].y, wv.y, a0);
                    a0 = fmaf(av[i].z, wv.z, a0);
                    a0 = fmaf(av[i].w, wv.w, a0);
                    acc[i][j] = a0;
                }
            }
        }
    }

    // ---------------- fused epilogue ----------------
    __syncthreads();                    // done with As/Ws reads
    __shared__ float L9[64 * 12];       // off3 logits (cols 0..8), +bias
    int n0 = rb * 64;
    const float* FTg = FT + ((size_t)s * Nn + n0) * Cc;
    float* FBg = featb + ((size_t)s * Nn + n0) * Cc;
    #pragma unroll
    for (int j = 0; j < 9; ++j) {
        int col = j * 16 + tx;
        if (col < 9) {
            float bv = bias[(col / 3) * 131 + col % 3];
            #pragma unroll
            for (int i = 0; i < 4; ++i)
                L9[(i * 16 + ty) * 12 + col] = acc[i][j] + bv;
        } else if (col < 137) {
            int ch = col - 9;
            float bv = bias[col + 256];
            #pragma unroll
            for (int i = 0; i < 4; ++i) {
                int row = i * 16 + ty;
                float lg = acc[i][j] + bv;                    // == old LOGc value
                FBg[(size_t)row * Cc + ch] = FTg[(size_t)row * Cc + ch] + lg;
            }
        }
    }
    __syncthreads();
    if (t < 192) {
        int row = t / 3, jv = t - row * 3;
        int n = n0 + row, v = n * 3 + jv;
        size_t vb = (size_t)s * Vv + v;
        float o0 = L9[row * 12 + jv * 3 + 0];
        float o1 = L9[row * 12 + jv * 3 + 1];
        float o2 = L9[row * 12 + jv * 3 + 2];
        const float* co = CO + ((size_t)s * Nn + n) * 3;
        coor[vb * 3 + 0] = co[0] + o0;
        coor[vb * 3 + 1] = co[1] + o1;
        coor[vb * 3 + 2] = co[2] + o2;
        const int* id = ID + ((size_t)s * Nn + n) * 3;
        int gi0 = (int)(o0 / 0.1f), gi1 = (int)(o1 / 0.1f), gi2 = (int)(o2 / 0.1f);
        int i0 = id[0] + gi0, i1 = id[1] + gi1, i2 = id[2] + gi2;
        indb[vb * 3 + 0] = i0; indb[vb * 3 + 1] = i1; indb[vb * 3 + 2] = i2;
        int h0 = min(max(i0, -512), 511) + 512;
        int h1 = min(max(i1, -512), 511) + 512;
        int h2 = min(max(i2, -512), 511) + 512;
        unsigned key = ((unsigned)h0 * 1024u + (unsigned)h1) * 1024u + (unsigned)h2;
        keys[vb] = key;
        idx0[vb] = (unsigned)v;
        atomicAdd(&hist0[(size_t)s * SB * 1024 + (size_t)(v >> 10) * 1024 + (key & 1023u)], 1u);
    }
}

// ---------------- deterministic column stats (byte-identical) ----------------
__global__ void colstats(const float* __restrict__ Y, float* __restrict__ part)
{
    int blk = blockIdx.x;
    int s = blk >> 6, b = blk & 63;
    const float* Yp = Y + (size_t)s * Nn * Cc + (size_t)b * 256 * Cc;
    int c = threadIdx.x;
    float sm = 0.f, sq = 0.f;
    for (int r = 0; r < 256; ++r) {
        float v = Yp[(size_t)r * Cc + c];
        sm += v; sq += v * v;
    }
    float* pp = part + ((size_t)s * 64 + b) * 2 * Cc;
    pp[c] = sm;
    pp[Cc + c] = sq;
}

__global__ void bnfinalize(const float* __restrict__ part, const float* __restrict__ g,
                           const float* __restrict__ be, float* __restrict__ ss)
{
    int s = blockIdx.x, c = threadIdx.x;
    const float* pp = part + (size_t)s * 64 * 2 * Cc;
    float sm = 0.f, sq = 0.f;
    for (int b = 0; b < 64; ++b) {
        sm += pp[(size_t)b * 2 * Cc + c];
        sq += pp[(size_t)b * 2 * Cc + Cc + c];
    }
    float m   = sm / (float)Nn;
    float var = sq / (float)Nn - m * m;
    float inv = 1.0f / sqrtf(var + 1e-5f);
    float sc  = g[c] * inv;
    ss[(size_t)s * 2 * Cc + c]      = sc;
    ss[(size_t)s * 2 * Cc + Cc + c] = be[c] - m * sc;
}

// ---------------- zero the 3 hist buffers ----------------
__global__ void zerok(uint4* __restrict__ p)
{
    p[(size_t)blockIdx.x * 256 + threadIdx.x] = make_uint4(0, 0, 0, 0);
}

// ---------------- fused scan + stable scatter (+ next-pass hist) ----------------
template<int PASS>
__global__ __launch_bounds__(512) void scat(
    const unsigned* __restrict__ kIn, const unsigned* __restrict__ iIn,
    unsigned* __restrict__ kOut, unsigned* __restrict__ iOut,
    const unsigned* __restrict__ hist, unsigned* __restrict__ nextH)
{   // grid: Bn*SB blocks, 512 threads, 1024 elems/block
    __shared__ unsigned hw[8 * 1024];   // per-wave digit counts -> exclusive wave offsets
    __shared__ unsigned tot[1024];      // digit totals -> binBase + my-block prefix
    int t = threadIdx.x, lane = t & 63, w = t >> 6;
    int blk = blockIdx.x, s = blk / SB, b = blk % SB;

    // wave-private zero of this wave's hw row (no sync needed: row is wave-private)
    #pragma unroll
    for (int i = 0; i < 16; ++i) hw[w * 1024 + i * 64 + lane] = 0u;

    // global hist scan: 2 digits/thread, block-prefix + totals
    const uint2* hs2 = (const uint2*)(hist + (size_t)s * SB * 1024);
    int d0 = 2 * t, d1 = 2 * t + 1;
    unsigned run0 = 0, run1 = 0, my0 = 0, my1 = 0;
    for (int bb = 0; bb < SB; ++bb) {
        uint2 v = hs2[bb * 512 + t];
        if (bb == b) { my0 = run0; my1 = run1; }
        run0 += v.x; run1 += v.y;
    }
    tot[d0] = run0; tot[d1] = run1;
    __syncthreads();
    for (int ofs = 1; ofs < 1024; ofs <<= 1) {
        unsigned a0 = (d0 >= ofs) ? tot[d0 - ofs] : 0u;
        unsigned a1 = (d1 >= ofs) ? tot[d1 - ofs] : 0u;
        __syncthreads();
        tot[d0] += a0; tot[d1] += a1;
        __syncthreads();
    }
    // tot[d] := binBase(exclusive over digits) + this block's prefix within digit
    tot[d0] = tot[d0] - run0 + my0;
    tot[d1] = tot[d1] - run1 + my1;

    // stable in-block ranking: wave chunks of 128, 2 slots of 64 (position order)
    size_t base = (size_t)s * Vv + (size_t)b * 1024;
    unsigned keyE[2], idxE[2], rkE[2], dE[2];
    #pragma unroll
    for (int e = 0; e < 2; ++e) {
        int pos = w * 128 + e * 64 + lane;
        keyE[e] = kIn[base + pos];
        idxE[e] = iIn[base + pos];
        unsigned d = (keyE[e] >> (PASS * 10)) & 1023u;
        dE[e] = d;
        unsigned long long m = ~0ull;
        #pragma unroll
        for (int bit = 0; bit < 10; ++bit) {
            bool bbit = (d >> bit) & 1u;
            unsigned long long bal = __ballot(bbit);
            m &= bbit ? bal : ~bal;
        }
        int lanesBelow = __popcll(m & ((1ull << lane) - 1ull));
        int cnt = __popcll(m);
        int leader = __ffsll((unsigned long long)m) - 1;
        unsigned basec = hw[w * 1024 + d];          // wave-lockstep read-before-write
        if (lane == leader) hw[w * 1024 + d] = basec + (unsigned)cnt;
        rkE[e] = basec + (unsigned)lanesBelow;
    }
    __syncthreads();
    // hw rows -> cross-wave exclusive offsets, in place (one thread per 2 digits)
    {
        unsigned r0 = 0, r1 = 0;
        for (int ww = 0; ww < 8; ++ww) {
            unsigned v0 = hw[ww * 1024 + d0], v1 = hw[ww * 1024 + d1];
            hw[ww * 1024 + d0] = r0; hw[ww * 1024 + d1] = r1;
            r0 += v0; r1 += v1;
        }
    }
    __syncthreads();
    #pragma unroll
    for (int e = 0; e < 2; ++e) {
        unsigned dest = tot[dE[e]] + hw[w * 1024 + dE[e]] + rkE[e];
        kOut[(size_t)s * Vv + dest] = keyE[e];
        iOut[(size_t)s * Vv + dest] = idxE[e];
        if constexpr (PASS < 2) {
            unsigned d2 = (keyE[e] >> ((PASS + 1) * 10)) & 1023u;
            atomicAdd(&nextH[(size_t)s * SB * 1024 + (size_t)(dest >> 10) * 1024 + d2], 1u);
        }
    }
}

// ---------------- group heads (per-block counts) ----------------
__global__ __launch_bounds__(512) void headsct(const unsigned* __restrict__ skeys,
                                               unsigned* __restrict__ hpart)
{
    int blk = blockIdx.x;
    int s = blk / HB, b = blk % HB;
    int i = b * 512 + threadIdx.x;
    size_t base = (size_t)s * Vv;
    unsigned k = skeys[base + i];
    bool head = (i == 0) || (skeys[base + i - 1] != k);
    __shared__ unsigned wsum[8];
    unsigned long long bal = __ballot(head);
    int lane = threadIdx.x & 63, wid = threadIdx.x >> 6;
    if (lane == 0) wsum[wid] = (unsigned)__popcll(bal);
    __syncthreads();
    if (threadIdx.x == 0) {
        unsigned tot = 0;
        for (int w = 0; w < 8; ++w) tot += wsum[w];
        hpart[s * HB + b] = tot;
    }
}

// ---------------- ranks: self-prefix over hpart + write group starts ----------------
__global__ __launch_bounds__(512) void ranksk(const unsigned* __restrict__ skeys,
                                              const unsigned* __restrict__ hpart,
                                              unsigned* __restrict__ start,
                                              unsigned* __restrict__ nu)
{
    int blk = blockIdx.x;
    int s = blk / HB, b = blk % HB;
    int t = threadIdx.x;
    __shared__ unsigned hp[HB];
    __shared__ unsigned pre[HB + 1];
    if (t < HB) hp[t] = hpart[s * HB + t];
    __syncthreads();
    if (t == 0) {
        unsigned run = 0;
        for (int i = 0; i < HB; ++i) { pre[i] = run; run += hp[i]; }
        pre[HB] = run;
    }
    __syncthreads();
    int i = b * 512 + t;
    size_t base = (size_t)s * Vv;
    unsigned k = skeys[base + i];
    bool head = (i == 0) || (skeys[base + i - 1] != k);
    unsigned long long bal = __ballot(head);
    int lane = t & 63, wid = t >> 6;
    __shared__ unsigned wsum[8];
    if (lane == 0) wsum[wid] = (unsigned)__popcll(bal);
    __syncthreads();
    unsigned wbase = 0;
    for (int w = 0; w < wid; ++w) wbase += wsum[w];
    unsigned lpre = (unsigned)__popcll(bal & ((1ull << lane) - 1ull));
    if (head)
        start[(size_t)s * (Vv + 1) + pre[b] + wbase + lpre] = (unsigned)i;
    if (b == 0 && t == 0) {
        nu[s] = pre[HB];
        start[(size_t)s * (Vv + 1) + pre[HB]] = (unsigned)Vv;
    }
}

// ---------------- output build: 1 wave per output row, float4 feat ----------------
__global__ __launch_bounds__(256) void outputk(
    const unsigned* __restrict__ sidx, const unsigned* __restrict__ start,
    const unsigned* __restrict__ nu, const int* __restrict__ indb,
    const float* __restrict__ coor, const float* __restrict__ featb,
    float* __restrict__ out)
{
    int wid = threadIdx.x >> 6, lane = threadIdx.x & 63;
    int g = blockIdx.x * 4 + wid;
    int s = g / Vv, u = g - s * Vv;
    size_t su = (size_t)s * Vv + u;
    bool valid = (unsigned)u < nu[s];
    float4* out4 = (float4*)out;
    int f = lane & 31, jlo = lane >> 5;
    if (valid) {
        const unsigned* st = start + (size_t)s * (Vv + 1);
        unsigned i0 = st[u], i1 = st[u + 1];
        unsigned c = i1 - i0;
        unsigned my = sidx[(size_t)s * Vv + i0 + ((unsigned)(lane & 3)) % c];
        unsigned sv[4];
        sv[0] = __shfl(my, 0); sv[1] = __shfl(my, 1);
        sv[2] = __shfl(my, 2); sv[3] = __shfl(my, 3);
        const float4* fb = (const float4*)(featb + (size_t)s * Nn * Cc);
        #pragma unroll
        for (int h = 0; h < 2; ++h) {
            int j = jlo + 2 * h;
            out4[(FEAT0 >> 2) + su * 128 + (size_t)j * 32 + f] =
                fb[(size_t)(sv[j] / 3) * 32 + f];
        }
        if (lane < 12)
            out[COOR0 + su * 12 + lane] =
                coor[((size_t)s * Vv + sv[lane / 3]) * 3 + lane % 3];
        else if (lane < 15)
            out[IND0 + su * 3 + (lane - 12)] =
                (float)indb[((size_t)s * Vv + sv[0]) * 3 + (lane - 12)];
        else if (lane == 15)
            out[MASK0 + su] = 1.f;
    } else {
        float4 z = make_float4(0.f, 0.f, 0.f, 0.f);
        #pragma unroll
        for (int h = 0; h < 2; ++h)
            out4[(FEAT0 >> 2) + su * 128 + (size_t)(jlo + 2 * h) * 32 + f] = z;
        if (lane < 12)       out[COOR0 + su * 12 + lane] = 0.f;
        else if (lane < 15)  out[IND0 + su * 3 + (lane - 12)] = 0.f;
        else if (lane == 15) out[MASK0 + su] = 0.f;
    }
}

// ---------------- host launch ----------------
extern "C" void kernel_launch(void* const* d_in, const int* in_sizes, int n_in,
                              void* d_out, int out_size, void* d_ws, size_t ws_size,
                              hipStream_t stream)
{
    const int*   ID  = (const int*)d_in[0];
    const float* CO  = (const float*)d_in[1];
    const float* FT  = (const float*)d_in[2];
    const float* W1  = (const float*)d_in[3];
    const float* b1  = (const float*)d_in[4];
    const float* g1  = (const float*)d_in[5];
    const float* be1 = (const float*)d_in[6];
    const float* W2  = (const float*)d_in[7];
    const float* b2  = (const float*)d_in[8];
    const float* g2  = (const float*)d_in[9];
    const float* be2 = (const float*)d_in[10];
    const float* W3  = (const float*)d_in[11];
    const float* b3  = (const float*)d_in[12];
    float* out = (float*)d_out;

    char* wsc = (char*)d_ws;
    size_t off = 0;
    auto alloc = [&](size_t elems) -> void* {
        void* p = wsc + off;
        off += ((elems * 4 + 255) & ~(size_t)255);
        return p;
    };
    float*    H1b   = (float*)alloc((size_t)Bn * Nn * Cc);
    float*    H2b   = (float*)alloc((size_t)Bn * Nn * Cc);
    float*    PART  = (float*)alloc((size_t)Bn * 64 * 2 * Cc);
    float*    SS    = (float*)alloc((size_t)Bn * 2 * Cc);
    float*    COORb = (float*)alloc((size_t)Bn * Vv * 3);
    int*      INDB  = (int*)alloc((size_t)Bn * Vv * 3);
    float*    FEATB = (float*)alloc((size_t)Bn * Nn * Cc);
    unsigned* KA    = (unsigned*)alloc((size_t)Bn * Vv);
    unsigned* IA    = (unsigned*)alloc((size_t)Bn * Vv);
    unsigned* KB    = (unsigned*)alloc((size_t)Bn * Vv);
    unsigned* IB    = (unsigned*)alloc((size_t)Bn * Vv);
    unsigned* H0h   = (unsigned*)alloc((size_t)Bn * SB * 1024);  // three hist buffers,
    unsigned* H1h   = (unsigned*)alloc((size_t)Bn * SB * 1024);  // contiguous (sizes are
    unsigned* H2h   = (unsigned*)alloc((size_t)Bn * SB * 1024);  // multiples of 256B)
    unsigned* HP    = (unsigned*)alloc((size_t)Bn * HB);
    unsigned* NUp   = (unsigned*)alloc((size_t)Bn);
    unsigned* STp   = (unsigned*)alloc((size_t)Bn * (Vv + 1));
    (void)in_sizes; (void)n_in; (void)out_size; (void)ws_size;

    // zero all 3 hist buffers: 3 * Bn*SB*1024 u32 = 294912 u32 = 73728 uint4
    zerok<<<288, 256, 0, stream>>>((uint4*)H0h);

    // MLP (BN fused into next layer's A-load; stats byte-identical)
    gemm_t<false><<<Bn * 256, 256, 0, stream>>>(FT, W1, b1, nullptr, H1b);
    colstats<<<Bn * 64, 128, 0, stream>>>(H1b, PART);
    bnfinalize<<<Bn, 128, 0, stream>>>(PART, g1, be1, SS);
    gemm_t<true><<<Bn * 256, 256, 0, stream>>>(H1b, W2, b2, SS, H2b);
    colstats<<<Bn * 64, 128, 0, stream>>>(H2b, PART);
    bnfinalize<<<Bn, 128, 0, stream>>>(PART, g2, be2, SS);

    // layer 3 + fused vote prep (writes featb/coor/ind/keys/hist0 directly)
    gemm3_fused<<<Bn * 256, 256, 0, stream>>>(H2b, W3, b3, SS, FT, CO, ID,
                                              FEATB, COORb, INDB, KA, IA, H0h);

    // radix sort: 3 x 10-bit, scan fused into scatter, hist fused into prev pass
    scat<0><<<Bn * SB, 512, 0, stream>>>(KA, IA, KB, IB, H0h, H1h);
    scat<1><<<Bn * SB, 512, 0, stream>>>(KB, IB, KA, IA, H1h, H2h);
    scat<2><<<Bn * SB, 512, 0, stream>>>(KA, IA, KB, IB, H2h, nullptr);

    // grouping
    headsct<<<Bn * HB, 512, 0, stream>>>(KB, HP);
    ranksk<<<Bn * HB, 512, 0, stream>>>(KB, HP, STp, NUp);

    // output
    outputk<<<Bn * Vv / 4, 256, 0, stream>>>(IB, STp, NUp, INDB, COORb, FEATB, out);
}